// Round 2
// 3031.316 us; speedup vs baseline: 1.0974x; 1.0974x over previous
//
#include <hip/hip_runtime.h>
#include <hip/hip_bf16.h>

#define Bq 256
#define Nn 256
#define Dd 256
#define Uu 256

using bf16 = __hip_bfloat16;

typedef __attribute__((ext_vector_type(8))) short s16x8;
typedef __attribute__((ext_vector_type(4))) float f32x4;

__device__ __forceinline__ float bu2f(unsigned short u) {
  return __uint_as_float(((unsigned)u) << 16);
}
__device__ __forceinline__ unsigned short f2bu(float f) {
  union { bf16 h; unsigned short u; } c; c.h = __float2bfloat16(f); return c.u;
}
__device__ __forceinline__ float sigf(float x) { return 1.0f / (1.0f + __expf(-x)); }
__device__ __forceinline__ float tanh_(float x) { return 2.0f / (1.0f + __expf(-2.0f * x)) - 1.0f; }
__device__ __forceinline__ s16x8 asv(uint4 x) {
  union { uint4 u; s16x8 v; } c; c.u = x; return c.v;
}
#define MFMA16(a, b, c) __builtin_amdgcn_mfma_f32_16x16x32_bf16(a, b, c, 0, 0, 0)

// ---- weight prep: build MFMA B-fragments (bf16) for wiou and wf ----
// wiouB frag (g,nt,kt), lane l, elem e:  = hiou[(kt*32+(l>>4)*8+e)*768 + g*256+nt*16+(l&15)]
// wfB   frag (nt,kt):                    = hf  [(kt*32+(l>>4)*8+e)*256 +        nt*16+(l&15)]
__global__ __launch_bounds__(256) void prep_weights(
    const float* __restrict__ hiou, const float* __restrict__ hf,
    bf16* __restrict__ wiouB, bf16* __restrict__ wfB) {
  int idx = blockIdx.x * 256 + threadIdx.x;  // 262144 total
  int e = idx & 7, l = (idx >> 3) & 63, kt = (idx >> 9) & 7;
  int k = kt * 32 + (l >> 4) * 8 + e;
  if (idx < 196608) {
    int nt = (idx >> 12) & 15, g = idx >> 16;
    wiouB[idx] = __float2bfloat16(hiou[k * 768 + g * 256 + nt * 16 + (l & 15)]);
  } else {
    int t = idx - 196608;
    int nt = (t >> 12) & 15;
    wfB[t] = __float2bfloat16(hf[k * 256 + nt * 16 + (l & 15)]);
  }
}

// ---- node-info table: nd[blk][t][m] = tgt | par<<8 | om<<16 | pm<<17 ----
__global__ __launch_bounds__(256) void prep_nd(
    const int* __restrict__ parents, const int* __restrict__ post,
    unsigned* __restrict__ ndg) {
  int idx = blockIdx.x * 256 + threadIdx.x;  // 65536
  int b = idx >> 8, t = idx & 255;
  int po = post[b * 256 + t];
  int om = po >= 0;
  int tgt = om ? po : 0;
  int praw = parents[b * 256 + tgt];
  int pm = (praw >= 0) && om;
  int par = praw >= 0 ? praw : 0;
  unsigned word = (unsigned)(tgt & 255) | ((unsigned)(par & 255) << 8) |
                  ((unsigned)om << 16) | ((unsigned)pm << 17);
  ndg[(b >> 4) * 4096 + t * 16 + (b & 15)] = word;
}

// ---- phase 1: fiou_xb = inputs @ x_fiou + bias (VALU, unchanged) ----
__global__ __launch_bounds__(256) void xproj(
    const float* __restrict__ x, const float* __restrict__ w,
    const float* __restrict__ bias, bf16* __restrict__ out) {
  __shared__ float xs[Dd][16];
  const int tid = threadIdx.x;
  const int row0 = blockIdx.x * 16;
  for (int i = 0; i < 16; ++i) {
    int idx = i * 256 + tid;
    int r = idx >> 8, k = idx & 255;
    xs[k][r] = x[(size_t)(row0 + r) * Dd + k];
  }
  __syncthreads();
  const int c0 = tid * 4;
  float4 bv = *(const float4*)(bias + c0);
  float acc[16][4];
#pragma unroll
  for (int r = 0; r < 16; ++r) {
    acc[r][0] = bv.x; acc[r][1] = bv.y; acc[r][2] = bv.z; acc[r][3] = bv.w;
  }
  for (int k = 0; k < Dd; ++k) {
    float4 wv = *(const float4*)(w + (size_t)k * 1024 + c0);
    const float4* xr = (const float4*)xs[k];
    float4 x0 = xr[0], x1 = xr[1], x2 = xr[2], x3 = xr[3];
    float xv[16] = {x0.x, x0.y, x0.z, x0.w, x1.x, x1.y, x1.z, x1.w,
                    x2.x, x2.y, x2.z, x2.w, x3.x, x3.y, x3.z, x3.w};
#pragma unroll
    for (int r = 0; r < 16; ++r) {
      acc[r][0] += xv[r] * wv.x;
      acc[r][1] += xv[r] * wv.y;
      acc[r][2] += xv[r] * wv.z;
      acc[r][3] += xv[r] * wv.w;
    }
  }
#pragma unroll
  for (int r = 0; r < 16; ++r) {
    union { ushort4 u4; bf16 b[4]; } pk;
    pk.b[0] = __float2bfloat16(acc[r][0]);
    pk.b[1] = __float2bfloat16(acc[r][1]);
    pk.b[2] = __float2bfloat16(acc[r][2]);
    pk.b[3] = __float2bfloat16(acc[r][3]);
    *(ushort4*)(&out[(size_t)(row0 + r) * 1024 + c0]) = pk.u4;
  }
}

// ---- phase 2: MFMA scan, STREAMED wiou B-fragments ----
// 16 blocks x 512 threads (8 waves). Block owns 16 batches (M=16).
// Wave w owns output cols j in [32w, 32w+32) for gates i,o,u and f.
// wf B-frags stay LDS-resident (128 KB). wiou B-frags (384 KB/block/step)
// are STREAMED from L2 through a 2-slot x 6-frag register ring: they cannot
// be register-resident (192 regs/wave) at the mandatory 2-waves/SIMD
// occupancy (256-reg cap) -- the previous version spilled them to scratch.
#define LDH 264
#define SCAN_LDS (131072 + 2 * 16 * LDH * 2)
extern __shared__ char smem[];

__global__ __launch_bounds__(512, 2) void scan3(
    const unsigned short* __restrict__ fiou, const unsigned short* __restrict__ wiouB,
    const unsigned short* __restrict__ wfB, const unsigned* __restrict__ ndg,
    float* __restrict__ X, float* __restrict__ gcs) {
  unsigned short* wf_l  = (unsigned short*)smem;            // 65536 elems
  unsigned short* h_lds = (unsigned short*)(smem + 131072); // 16 x LDH
  unsigned short* o_lds = h_lds + 16 * LDH;                 // 16 x LDH

  const int tid = threadIdx.x;
  const int w = tid >> 6, l = tid & 63;
  const int lm = l & 15, lq = l >> 4;
  const int blk = blockIdx.x;
  const int jj = 32 * w + lm;

  // stage wf B-fragments into LDS (resident across all steps)
  {
    const uint4* s = (const uint4*)wfB;
    uint4* d = (uint4*)wf_l;
    for (int i = tid; i < 8192; i += 512) d[i] = s[i];
  }
  const unsigned* ndb = ndg + blk * 4096;
  const uint4* ndb4 = (const uint4*)ndb;
  uint4 cur4 = ndb4[lq];
  unsigned cur_g = ndb[tid >> 5];
  const uint4* wp = (const uint4*)wiouB;
  __syncthreads();

  for (int t = 0; t < Nn; ++t) {
    // A) h-gather loads: 16 rows of csh (X) -- depends on prev step's B3
    const int r16 = tid >> 5, c8 = (tid & 31) * 8;
    int nrh = ((blk * 16 + r16) << 8) + (int)(cur_g & 255);
    const float* xr = X + ((size_t)nrh << 8) + c8;
    float4 a0 = ((const float4*)xr)[0];
    float4 a1 = ((const float4*)xr)[1];

    unsigned ndr[4] = {cur4.x, cur4.y, cur4.z, cur4.w};

    // B) issue ALL per-step gating / RMW loads up front (latency hiding).
    //    Safe: fiou is read-only; gcs[tgt], X[par], gcs[par] were last
    //    written before the previous B3; each (row,col) RMW element is
    //    loaded and stored by the SAME thread within this step.
    unsigned short rxi[2][4], rxo[2][4], rxu[2][4], rxf[2][4];
    float rgc[2][4], xold[2][4], gold[2][4];
#pragma unroll
    for (int r = 0; r < 4; ++r) {
      int tgt = ndr[r] & 255, par = (ndr[r] >> 8) & 255;
      int nb = (blk * 16 + 4 * lq + r) << 8;
      int nrT = nb + tgt, nrP = nb + par;
      const unsigned short* fT = fiou + ((size_t)nrT << 10);
      const unsigned short* fP = fiou + ((size_t)nrP << 10);
#pragma unroll
      for (int ts = 0; ts < 2; ++ts) {
        int j = jj + ts * 16;
        rxi[ts][r] = fT[256 + j];
        rxo[ts][r] = fT[512 + j];
        rxu[ts][r] = fT[768 + j];
        rxf[ts][r] = fP[j];
        rgc[ts][r]  = gcs[((size_t)nrT << 8) + j];
        xold[ts][r] = X[((size_t)nrP << 8) + j];
        gold[ts][r] = gcs[((size_t)nrP << 8) + j];
      }
    }

    // C) wiou stream prologue: kt = 0,1 into the 2-slot ring (L2-resident)
    uint4 st[2][3][2];
#pragma unroll
    for (int g = 0; g < 3; ++g)
#pragma unroll
      for (int ts = 0; ts < 2; ++ts) {
        st[0][g][ts] = wp[((g * 16 + (2 * w + ts)) * 8 + 0) * 64 + l];
        st[1][g][ts] = wp[((g * 16 + (2 * w + ts)) * 8 + 1) * 64 + l];
      }

    // D) h convert -> LDS
    {
      ushort4 p0, p1;
      p0.x = f2bu(a0.x); p0.y = f2bu(a0.y); p0.z = f2bu(a0.z); p0.w = f2bu(a0.w);
      p1.x = f2bu(a1.x); p1.y = f2bu(a1.y); p1.z = f2bu(a1.z); p1.w = f2bu(a1.w);
      *(ushort4*)&h_lds[r16 * LDH + c8] = p0;
      *(ushort4*)&h_lds[r16 * LDH + c8 + 4] = p1;
    }
    __syncthreads();  // B1: h_lds ready

    // prefetch next step's node info
    const int tn = t < Nn - 1 ? t + 1 : t;
    uint4 nxt4 = ndb4[tn * 4 + lq];
    unsigned nxt_g = ndb[tn * 16 + (tid >> 5)];

    // E) iou MFMA: h(16x256) @ wiou(256x768), B streamed 2 kt ahead
    f32x4 z4 = {0.f, 0.f, 0.f, 0.f};
    f32x4 aI[2] = {z4, z4}, aO[2] = {z4, z4}, aU[2] = {z4, z4};
#pragma unroll
    for (int kt = 0; kt < 8; ++kt) {
      uint4 av = *(const uint4*)&h_lds[lm * LDH + kt * 32 + lq * 8];
      s16x8 a = asv(av);
#pragma unroll
      for (int ts = 0; ts < 2; ++ts) {
        aI[ts] = MFMA16(a, asv(st[kt & 1][0][ts]), aI[ts]);
        aO[ts] = MFMA16(a, asv(st[kt & 1][1][ts]), aO[ts]);
        aU[ts] = MFMA16(a, asv(st[kt & 1][2][ts]), aU[ts]);
      }
      if (kt < 6) {  // refill consumed slot with kt+2 (static after unroll)
#pragma unroll
        for (int g = 0; g < 3; ++g)
#pragma unroll
          for (int ts = 0; ts < 2; ++ts)
            st[kt & 1][g][ts] = wp[((g * 16 + (2 * w + ts)) * 8 + (kt + 2)) * 64 + l];
      }
    }

    // F) gating (registers; lane owns (m = 4*lq+r, j = jj+16*ts))
    float mem_[2][4], out_[2][4];
#pragma unroll
    for (int ts = 0; ts < 2; ++ts)
#pragma unroll
      for (int r = 0; r < 4; ++r) {
        float I = aI[ts][r] + bu2f(rxi[ts][r]);
        float O = aO[ts][r] + bu2f(rxo[ts][r]);
        float Uv = aU[ts][r] + bu2f(rxu[ts][r]);
        float memv = sigf(I) * tanh_(Uv) + rgc[ts][r];
        float outv = sigf(O) * tanh_(memv);
        mem_[ts][r] = memv;
        out_[ts][r] = outv;
        o_lds[(4 * lq + r) * LDH + jj + ts * 16] = f2bu(outv);
      }
    __syncthreads();  // B2: o_lds ready

    // G) f MFMA: out(16x256) @ wf(256x256), wf frags LDS-resident
    f32x4 aF[2] = {z4, z4};
#pragma unroll
    for (int kt = 0; kt < 8; ++kt) {
      uint4 av = *(const uint4*)&o_lds[lm * LDH + kt * 32 + lq * 8];
      s16x8 a = asv(av);
#pragma unroll
      for (int ts = 0; ts < 2; ++ts) {
        uint4 bv = *(const uint4*)&wf_l[(((2 * w + ts) * 8 + kt) * 64 + l) * 8];
        aF[ts] = MFMA16(a, asv(bv), aF[ts]);
      }
    }

    // H) epilogue: hs write + parent csh/gcs accumulate (olds preloaded)
#pragma unroll
    for (int ts = 0; ts < 2; ++ts)
#pragma unroll
      for (int r = 0; r < 4; ++r) {
        unsigned nd_ = ndr[r];
        int tgt = nd_ & 255, par = (nd_ >> 8) & 255;
        int nb = (blk * 16 + 4 * lq + r) << 8;
        int j = jj + ts * 16;
        float AF = aF[ts][r] + bu2f(rxf[ts][r]);
        float gated = sigf(AF) * mem_[ts][r];
        if (nd_ & 0x10000u) X[((size_t)(nb + tgt) << 8) + j] = out_[ts][r];
        if (nd_ & 0x20000u) {
          X[((size_t)(nb + par) << 8) + j] = xold[ts][r] + out_[ts][r];
          gcs[((size_t)(nb + par) << 8) + j] = gold[ts][r] + gated;
        }
      }
    __syncthreads();  // B3: epilogue visible before next h-gather
    cur4 = nxt4;
    cur_g = nxt_g;
  }
}

extern "C" void kernel_launch(void* const* d_in, const int* in_sizes, int n_in,
                              void* d_out, int out_size, void* d_ws, size_t ws_size,
                              hipStream_t stream) {
  const float* inputs = (const float*)d_in[0];
  const int* parents  = (const int*)d_in[1];
  const int* post     = (const int*)d_in[2];
  const float* xw     = (const float*)d_in[3];
  const float* hf     = (const float*)d_in[4];
  const float* hiou   = (const float*)d_in[5];
  const float* bias   = (const float*)d_in[6];
  float* X = (float*)d_out;  // csh-then-hs buffer

  // ws layout (~192.8 MiB):
  //   [0, 128 MiB)   fiou_xb bf16  (B*N*4U)
  //   +134217728     gcs fp32      (B*N*U)   64 MiB
  //   +201326592     wiouB bf16    384 KiB
  //   +201719808     wfB bf16      128 KiB
  //   +201850880     ndg u32       256 KiB
  char* ws = (char*)d_ws;
  bf16* fiou     = (bf16*)ws;
  float* gcs     = (float*)(ws + (size_t)134217728);
  bf16* wiouB    = (bf16*)(ws + (size_t)201326592);
  bf16* wfB      = (bf16*)(ws + (size_t)201719808);
  unsigned* ndg  = (unsigned*)(ws + (size_t)201850880);

  hipMemsetAsync(X, 0, (size_t)Bq * Nn * Uu * sizeof(float), stream);
  hipMemsetAsync(gcs, 0, (size_t)Bq * Nn * Uu * sizeof(float), stream);

  hipFuncSetAttribute(reinterpret_cast<const void*>(scan3),
                      hipFuncAttributeMaxDynamicSharedMemorySize, SCAN_LDS);

  prep_weights<<<1024, 256, 0, stream>>>(hiou, hf, wiouB, wfB);
  prep_nd<<<256, 256, 0, stream>>>(parents, post, ndg);
  xproj<<<(Bq * Nn) / 16, 256, 0, stream>>>(inputs, xw, bias, (bf16*)fiou);
  scan3<<<16, 512, SCAN_LDS, stream>>>((const unsigned short*)fiou,
                                       (const unsigned short*)wiouB,
                                       (const unsigned short*)wfB,
                                       ndg, X, gcs);
}